// Round 3
// baseline (219.137 us; speedup 1.0000x reference)
//
#include <hip/hip_runtime.h>

// Reference collapses: softmax over a size-1 key axis == 1.0, so
// out[bn,t,:] = padded[bn,t,:] + (masked_mean_t(padded[bn]) @ Wv + bv).
// q/k/rope/positions/sum_token are dead code.
//
// R7: single fused kernel (single dispatch is mandatory: R6's 2-kernel
// split showed each extra dispatch costs ~10-15us of gap).  Fixes vs R5
// (75us, VGPR_Count=64 proved the compiler DROPPED tile residency and
// re-read padded in the store phase):
//   1. asm "+v" pin on every tile register after the colsum -> compiler
//      cannot rematerialize; store phase is pure-write.
//   2. two bn per block (grid 256): one Wv pass feeds both matvecs ->
//      chip Wv L2 traffic 295 -> 147 MB; 32 upfront loads/thread for MLP.
//   3. nontemporal out stores (write-only data; keep L3 for padded) and
//      v-finalize folded into the store phase (one fewer barrier).
// Expected VGPR ~160-200 (residency proof), kernel ~45-55us.

#define DM 384
#define TT 128
#define C4 96          // DM / 4
#define NBLK 256       // 512 bn / 2 per block
#define NR  8          // row-groups (768 = 8 * 96)
#define RPT 16         // rows per thread per bn

typedef float f32x4 __attribute__((ext_vector_type(4)));

__device__ __forceinline__ void nt_store4(float4* p, const float4 v) {
    __builtin_nontemporal_store(*(const f32x4*)&v, (f32x4*)p);
}

__global__ __launch_bounds__(768) void fused_pair(
    const float* __restrict__ padded,
    const int*   __restrict__ masks,
    const float* __restrict__ Wv,
    const float* __restrict__ bv,
    float*       __restrict__ out)
{
    const int bn0 = blockIdx.x << 1;     // this block owns bn0, bn0+1
    const int t = threadIdx.x;
    const int c = t % C4;                // float4 column 0..95
    const int r = t / C4;                // row-group 0..7

    __shared__ float  w_sh[2][TT];
    __shared__ float4 part_sh[2][NR][C4];   // 24 KB
    __shared__ float  summ[2][DM];

    // masks first so their waitcnt clears before the tile loads drain
    int m = 0;
    if (t < 2 * TT) m = masks[bn0 * TT + t];  // t<128: bn0 row t; else bn1 row t-128

    const float4* __restrict__ p0 = (const float4*)padded + (size_t)bn0 * TT * C4;
    const float4* __restrict__ p1 = p0 + TT * C4;

    // ---- issue all 32 tile loads upfront (deep MLP) ----
    float4 x0[RPT], x1[RPT];
    #pragma unroll
    for (int i = 0; i < RPT; ++i) x0[i] = p0[(r + i * NR) * C4 + c];
    #pragma unroll
    for (int i = 0; i < RPT; ++i) x1[i] = p1[(r + i * NR) * C4 + c];

    if (t < TT)          w_sh[0][t]      = (float)m;
    else if (t < 2 * TT) w_sh[1][t - TT] = (float)m;
    __syncthreads();

    // ---- masked column partial sums for both bn ----
    float4 acc0 = make_float4(0.f, 0.f, 0.f, 0.f);
    float4 acc1 = make_float4(0.f, 0.f, 0.f, 0.f);
    #pragma unroll
    for (int i = 0; i < RPT; ++i) {
        const float w = w_sh[0][r + i * NR];
        acc0.x += x0[i].x * w; acc0.y += x0[i].y * w;
        acc0.z += x0[i].z * w; acc0.w += x0[i].w * w;
    }
    #pragma unroll
    for (int i = 0; i < RPT; ++i) {
        const float w = w_sh[1][r + i * NR];
        acc1.x += x1[i].x * w; acc1.y += x1[i].y * w;
        acc1.z += x1[i].z * w; acc1.w += x1[i].w * w;
    }
    part_sh[0][r][c] = acc0;
    part_sh[1][r][c] = acc1;

    // ---- pin tile registers: forbid rematerialization (R5's failure) ----
    #pragma unroll
    for (int i = 0; i < RPT; ++i) {
        asm volatile("" : "+v"(x0[i].x), "+v"(x0[i].y), "+v"(x0[i].z), "+v"(x0[i].w));
        asm volatile("" : "+v"(x1[i].x), "+v"(x1[i].y), "+v"(x1[i].z), "+v"(x1[i].w));
    }
    __syncthreads();

    // ---- finalize summaries: 192 threads, one column each ----
    if (t < 2 * C4) {
        const int s  = (t >= C4);
        const int cc = t - s * C4;
        float d0 = 0.f, d1 = 0.f, d2 = 0.f, d3 = 0.f;
        #pragma unroll
        for (int i = 0; i < 32; ++i) {
            d0 += w_sh[s][i];      d1 += w_sh[s][32 + i];
            d2 += w_sh[s][64 + i]; d3 += w_sh[s][96 + i];
        }
        const float inv = 1.0f / fmaxf((d0 + d1) + (d2 + d3), 1e-6f);

        float4 sm = part_sh[s][0][cc];
        #pragma unroll
        for (int g = 1; g < NR; ++g) {
            const float4 p = part_sh[s][g][cc];
            sm.x += p.x; sm.y += p.y; sm.z += p.z; sm.w += p.w;
        }
        sm.x *= inv; sm.y *= inv; sm.z *= inv; sm.w *= inv;
        ((float4*)summ[s])[cc] = sm;
    }
    __syncthreads();

    // ---- matvec for BOTH bn off one Wv pass (block reads Wv once) ----
    float4 a0 = make_float4(0.f, 0.f, 0.f, 0.f);
    float4 a1 = make_float4(0.f, 0.f, 0.f, 0.f);
    const float4* __restrict__ wv4 = (const float4*)Wv;
    const int e0 = r * (DM / NR);        // 48 Wv rows per row-group
    #pragma unroll 8
    for (int i = 0; i < DM / NR; ++i) {
        const int   e  = e0 + i;
        const float s0 = summ[0][e];     // LDS broadcast
        const float s1 = summ[1][e];
        const float4 w = wv4[(size_t)e * C4 + c];   // coalesced, L2-hot
        a0.x += s0 * w.x; a0.y += s0 * w.y; a0.z += s0 * w.z; a0.w += s0 * w.w;
        a1.x += s1 * w.x; a1.y += s1 * w.y; a1.z += s1 * w.z; a1.w += s1 * w.w;
    }
    part_sh[0][r][c] = a0;
    part_sh[1][r][c] = a1;
    __syncthreads();

    // ---- v-finalize per thread (8x redundant LDS broadcast, no barrier) ----
    float4 v0 = ((const float4*)bv)[c];
    float4 v1 = v0;
    #pragma unroll
    for (int g = 0; g < NR; ++g) {
        const float4 q0 = part_sh[0][g][c];
        const float4 q1 = part_sh[1][g][c];
        v0.x += q0.x; v0.y += q0.y; v0.z += q0.z; v0.w += q0.w;
        v1.x += q1.x; v1.y += q1.y; v1.z += q1.z; v1.w += q1.w;
    }

    // ---- store from resident registers (pure write, nontemporal) ----
    float4* __restrict__ o0 = (float4*)out + (size_t)bn0 * TT * C4;
    float4* __restrict__ o1 = o0 + TT * C4;
    #pragma unroll
    for (int i = 0; i < RPT; ++i) {
        float4 y = x0[i];
        y.x += v0.x; y.y += v0.y; y.z += v0.z; y.w += v0.w;
        nt_store4(&o0[(r + i * NR) * C4 + c], y);
    }
    #pragma unroll
    for (int i = 0; i < RPT; ++i) {
        float4 y = x1[i];
        y.x += v1.x; y.y += v1.y; y.z += v1.z; y.w += v1.w;
        nt_store4(&o1[(r + i * NR) * C4 + c], y);
    }
}

extern "C" void kernel_launch(void* const* d_in, const int* in_sizes, int n_in,
                              void* d_out, int out_size, void* d_ws, size_t ws_size,
                              hipStream_t stream) {
    const float* padded = (const float*)d_in[0];
    // d_in[1] sum_token, d_in[2] positions_3d, d_in[3..6] Wq/bq/Wk/bk: dead
    const float* Wv     = (const float*)d_in[7];
    const float* bv     = (const float*)d_in[8];
    const int*   masks  = (const int*)d_in[9];
    float* out = (float*)d_out;

    fused_pair<<<NBLK, 768, 0, stream>>>(padded, masks, Wv, bv, out);
}

// Round 4
// 205.226 us; speedup vs baseline: 1.0678x; 1.0678x over previous
//
#include <hip/hip_runtime.h>

// Reference collapses: softmax over a size-1 key axis == 1.0, so
// out[bn,t,:] = padded[bn,t,:] + (masked_mean_t(padded[bn]) @ Wv + bv).
// q/k/rope/positions/sum_token are dead code.
//
// R8: R5's single-dispatch structure (best so far, 75us) with the two
// diagnosed defects fixed:
//   1. R5's VGPR_Count=64 / R7's 84 proved tile residency was dropped or
//      spilled: default launch_bounds targets high occupancy.  Explicit
//      __launch_bounds__(768, 4) raises the VGPR cap to 128; residency
//      needs ~100 -> no spill, store phase is pure-write from registers.
//   2. 1 block/CU at 512 blocks -> TWO rounds: round-2 loads overlap
//      round-1 matvec/store drain, breaking the chip-wide lockstep that
//      left HBM idle between phases in single-round variants.
// Kept from R7: nontemporal out stores (out never re-read; keep L3 for
// padded), masks loaded before the 16 upfront tile loads, v-finalize
// folded into the store phase.  Expected VGPR ~100-110 (residency proof),
// kernel ~50-58us.

#define DM 384
#define TT 128
#define C4 96          // DM / 4
#define BN_TOT 512
#define NR  8          // row-groups (768 = 8 * 96)
#define RPT 16         // rows per thread

typedef float f32x4 __attribute__((ext_vector_type(4)));

__device__ __forceinline__ void nt_store4(float4* p, const float4 v) {
    __builtin_nontemporal_store(*(const f32x4*)&v, (f32x4*)p);
}

__global__ __launch_bounds__(768, 4) void fused_resident(
    const float* __restrict__ padded,
    const int*   __restrict__ masks,
    const float* __restrict__ Wv,
    const float* __restrict__ bv,
    float*       __restrict__ out)
{
    const int bn = blockIdx.x;
    const int t  = threadIdx.x;
    const int c  = t % C4;               // float4 column 0..95
    const int r  = t / C4;               // row-group 0..7

    __shared__ float  w_sh[TT];
    __shared__ float4 part_sh[NR][C4];   // 12 KB
    __shared__ float  summ[DM];

    // masks first so their waitcnt clears early
    int m = 0;
    if (t < TT) m = masks[bn * TT + t];

    const float4* __restrict__ p4 =
        (const float4*)padded + (size_t)bn * TT * C4;

    // ---- issue all 16 tile loads upfront (deep MLP) ----
    float4 x[RPT];
    #pragma unroll
    for (int i = 0; i < RPT; ++i) x[i] = p4[(r + i * NR) * C4 + c];

    if (t < TT) w_sh[t] = (float)m;
    __syncthreads();

    // ---- masked column partial sums, 4 accumulators ----
    float4 a0 = make_float4(0.f, 0.f, 0.f, 0.f);
    float4 a1 = make_float4(0.f, 0.f, 0.f, 0.f);
    float4 a2 = make_float4(0.f, 0.f, 0.f, 0.f);
    float4 a3 = make_float4(0.f, 0.f, 0.f, 0.f);
    #pragma unroll
    for (int i = 0; i < 4; ++i) {
        const float w0 = w_sh[r + (4 * i)     * NR];
        const float w1 = w_sh[r + (4 * i + 1) * NR];
        const float w2 = w_sh[r + (4 * i + 2) * NR];
        const float w3 = w_sh[r + (4 * i + 3) * NR];
        const float4 x0 = x[4 * i], x1 = x[4 * i + 1];
        const float4 x2 = x[4 * i + 2], x3 = x[4 * i + 3];
        a0.x += x0.x * w0; a0.y += x0.y * w0; a0.z += x0.z * w0; a0.w += x0.w * w0;
        a1.x += x1.x * w1; a1.y += x1.y * w1; a1.z += x1.z * w1; a1.w += x1.w * w1;
        a2.x += x2.x * w2; a2.y += x2.y * w2; a2.z += x2.z * w2; a2.w += x2.w * w2;
        a3.x += x3.x * w3; a3.y += x3.y * w3; a3.z += x3.z * w3; a3.w += x3.w * w3;
    }
    a0.x += a1.x + a2.x + a3.x; a0.y += a1.y + a2.y + a3.y;
    a0.z += a1.z + a2.z + a3.z; a0.w += a1.w + a2.w + a3.w;
    part_sh[r][c] = a0;

    // ---- pin tile registers: forbid rematerialization ----
    #pragma unroll
    for (int i = 0; i < RPT; ++i) {
        asm volatile("" : "+v"(x[i].x), "+v"(x[i].y), "+v"(x[i].z), "+v"(x[i].w));
    }
    __syncthreads();

    // ---- finalize summary (96 threads; denom via 4 parallel chains) ----
    if (t < C4) {
        float d0 = 0.f, d1 = 0.f, d2 = 0.f, d3 = 0.f;
        #pragma unroll
        for (int i = 0; i < 32; ++i) {
            d0 += w_sh[i];      d1 += w_sh[32 + i];
            d2 += w_sh[64 + i]; d3 += w_sh[96 + i];
        }
        const float inv = 1.0f / fmaxf((d0 + d1) + (d2 + d3), 1e-6f);

        float4 s = part_sh[0][t];
        #pragma unroll
        for (int g = 1; g < NR; ++g) {
            const float4 p = part_sh[g][t];
            s.x += p.x; s.y += p.y; s.z += p.z; s.w += p.w;
        }
        s.x *= inv; s.y *= inv; s.z *= inv; s.w *= inv;
        ((float4*)summ)[t] = s;
    }
    __syncthreads();

    // ---- matvec: row-group r covers Wv rows [r*48, r*48+48) ----
    float4 a = make_float4(0.f, 0.f, 0.f, 0.f);
    const float4* __restrict__ wv4 = (const float4*)Wv;
    const int e0 = r * (DM / NR);
    #pragma unroll 8
    for (int i = 0; i < DM / NR; ++i) {
        const int   e = e0 + i;
        const float s = summ[e];                    // LDS broadcast
        const float4 w = wv4[(size_t)e * C4 + c];   // coalesced, L2-hot
        a.x += s * w.x; a.y += s * w.y; a.z += s * w.z; a.w += s * w.w;
    }
    part_sh[r][c] = a;
    __syncthreads();

    // ---- v-finalize per thread (LDS broadcast, no extra barrier) ----
    float4 v = ((const float4*)bv)[c];
    #pragma unroll
    for (int g = 0; g < NR; ++g) {
        const float4 q = part_sh[g][c];
        v.x += q.x; v.y += q.y; v.z += q.z; v.w += q.w;
    }

    // ---- store from resident registers (pure write, nontemporal) ----
    float4* __restrict__ o4 = (float4*)out + (size_t)bn * TT * C4;
    #pragma unroll
    for (int i = 0; i < RPT; ++i) {
        float4 y = x[i];
        y.x += v.x; y.y += v.y; y.z += v.z; y.w += v.w;
        nt_store4(&o4[(r + i * NR) * C4 + c], y);
    }
}

extern "C" void kernel_launch(void* const* d_in, const int* in_sizes, int n_in,
                              void* d_out, int out_size, void* d_ws, size_t ws_size,
                              hipStream_t stream) {
    const float* padded = (const float*)d_in[0];
    // d_in[1] sum_token, d_in[2] positions_3d, d_in[3..6] Wq/bq/Wk/bk: dead
    const float* Wv     = (const float*)d_in[7];
    const float* bv     = (const float*)d_in[8];
    const int*   masks  = (const int*)d_in[9];
    float* out = (float*)d_out;

    fused_resident<<<BN_TOT, 768, 0, stream>>>(padded, masks, Wv, bv, out);
}